// Round 6
// baseline (400.715 us; speedup 1.0000x reference)
//
#include <hip/hip_runtime.h>

// ============================================================================
// Fully-connected e3nn-style tensor product, IRREPS = 32x0e + 32x1o + 32x2e
// BATCH=8192, FEAT=288, 11 uvw paths, weights flat [360448].
//
// Kernel 1 (setup): device-side replication of the reference Wigner-3j
//   construction (complex CG + real-SH change of basis + Frobenius norm)
//   into __device__ g_w3 (11 paths x 128 floats, layout [(i*d2+j)*do + k]).
// Kernel 2 (main): lane = batch row. grid = (128 z-tiles, 9 (io,k) slices,
//   2 w-halves). Per path: held-side slice in VGPRs, streamed side per
//   channel, CG via c[i]-precompute, weights via wave-uniform s_load,
//   32 fmacs/channel-pair into acc. One writer per output element.
// ============================================================================

__device__ float g_w3[11 * 128];

// ---------------- Wigner 3j setup --------------------------------------------

__device__ __forceinline__ double dfact(int n) {
    double r = 1.0;
    for (int i = 2; i <= n; ++i) r *= (double)i;
    return r;
}

__device__ double cg_coef(int j1, int m1, int j2, int m2, int j3, int m3) {
    if (m1 + m2 != m3) return 0.0;
    int lo = (j1 > j2) ? (j1 - j2) : (j2 - j1);
    if (j3 > j1 + j2 || j3 < lo) return 0.0;
    double pre = (2.0 * j3 + 1.0) * dfact(j3 + j1 - j2) * dfact(j3 - j1 + j2) *
                 dfact(j1 + j2 - j3) / dfact(j1 + j2 + j3 + 1);
    pre *= dfact(j3 + m3) * dfact(j3 - m3) * dfact(j1 - m1) * dfact(j1 + m1) *
           dfact(j2 - m2) * dfact(j2 + m2);
    double s = 0.0;
    for (int k = 0; k <= j1 + j2 - j3; ++k) {
        int a1 = j1 + j2 - j3 - k, a2 = j1 - m1 - k, a3 = j2 + m2 - k;
        int a4 = j3 - j2 + m1 + k, a5 = j3 - j1 - m2 + k;
        if (a1 < 0 || a2 < 0 || a3 < 0 || a4 < 0 || a5 < 0) continue;
        double t = 1.0 / (dfact(k) * dfact(a1) * dfact(a2) * dfact(a3) * dfact(a4) * dfact(a5));
        s += (k & 1) ? -t : t;
    }
    return sqrt(pre) * s;
}

// Q[a][mi] for real-SH basis change (scratch-free, matches reference _q)
__device__ __forceinline__ void qval(int l, int a, int mi, double& re, double& im) {
    re = 0.0; im = 0.0;
    const double inv = 0.7071067811865475244;
    int ma = a - l, mc = mi - l;
    if (ma == 0) { if (mc == 0) re = 1.0; return; }
    if (ma > 0) {
        if (mc == ma)        re = (ma & 1) ? -inv : inv;
        else if (mc == -ma)  re = inv;
    } else {
        int mm = -ma;
        if (mc == ma)        im = inv;
        else if (mc == -ma)  im = -((mm & 1) ? -inv : inv);
    }
}

__global__ void wigner3j_setup() {
    const int L1[11] = {0,0,0,1,1,1,1,2,2,2,2};
    const int L2[11] = {0,1,2,0,1,1,2,0,1,2,2};
    const int L3[11] = {0,1,2,1,0,2,1,2,1,0,2};
    const int p = blockIdx.x;
    const int l1 = L1[p], l2 = L2[p], l3 = L3[p];
    const int d1 = 2 * l1 + 1, d2 = 2 * l2 + 1, d3 = 2 * l3 + 1;
    const int n = d1 * d2 * d3;

    __shared__ double sre[125], sim[125];
    __shared__ double s_scale;
    __shared__ int s_im;

    const int e = threadIdx.x;
    if (e < n) {
        int a = e / (d2 * d3);
        int r = e - a * d2 * d3;
        int b = r / d3;
        int c = r - b * d3;
        double tre = 0.0, tim = 0.0;
        for (int m1 = -l1; m1 <= l1; ++m1) {
            for (int m2 = -l2; m2 <= l2; ++m2) {
                int m3 = -(m1 + m2);
                if (m3 < -l3 || m3 > l3) continue;
                int ex = l1 - l2 - m3;
                double sgn = (ex % 2 != 0) ? -1.0 : 1.0;
                double C = sgn * cg_coef(l1, m1, l2, m2, l3, -m3);
                if (C == 0.0) continue;
                double r1, i1, r2, i2, r3, i3;
                qval(l1, a, m1 + l1, r1, i1);
                qval(l2, b, m2 + l2, r2, i2);
                qval(l3, c, m3 + l3, r3, i3);
                i1 = -i1; i2 = -i2; i3 = -i3;  // conj
                double rr = r1 * r2 - i1 * i2;
                double ri = r1 * i2 + i1 * r2;
                double fr = rr * r3 - ri * i3;
                double fi = rr * i3 + ri * r3;
                tre += C * fr;
                tim += C * fi;
            }
        }
        sre[e] = tre; sim[e] = tim;
    }
    __syncthreads();
    if (threadIdx.x == 0) {
        double sar = 0.0, sai = 0.0;
        for (int i = 0; i < n; ++i) { sar += fabs(sre[i]); sai += fabs(sim[i]); }
        int useim = (sar >= sai) ? 0 : 1;
        double ss = 0.0;
        for (int i = 0; i < n; ++i) { double v = useim ? sim[i] : sre[i]; ss += v * v; }
        s_scale = 1.0 / sqrt(ss);
        s_im = useim;
    }
    __syncthreads();
    if (e < n) {
        double v = s_im ? sim[e] : sre[e];
        g_w3[p * 128 + e] = (float)(v * s_scale);
    }
}

// ---------------- Main tensor-product kernel ---------------------------------
//
// do_path: held side (DH comps/channel, 32 channels in VGPRs, chunked),
// streamed side (DS comps/channel, re-read per channel), dense w3 slice for
// this k. HX1: held side is x1 (weight index u*1024 uses held channel).
// NW=16 output columns starting at the caller-applied w0 offset.

template <int DH, int DS, int D1, int D2, int DO, bool HX1, int NW>
__device__ __forceinline__ void do_path(const float* __restrict__ xh,
                                        const float* __restrict__ xs,
                                        const float* __restrict__ Wp,
                                        const float* __restrict__ w3p,
                                        int k, float* __restrict__ acc) {
    // w3 slice for this k: w3l[held][stream]
    float w3l[DH][DS];
#pragma unroll
    for (int ih = 0; ih < DH; ++ih) {
#pragma unroll
        for (int is = 0; is < DS; ++is) {
            const int i = HX1 ? ih : is;  // x1 component
            const int j = HX1 ? is : ih;  // x2 component
            w3l[ih][is] = w3p[(i * D2 + j) * DO + k];
        }
    }
    constexpr int CH = (DH >= 5) ? 16 : 32;  // held-channel chunk (VGPR cap)
#pragma unroll 1
    for (int h0 = 0; h0 < 32; h0 += CH) {
        float H[CH * DH];
#pragma unroll
        for (int h = 0; h < CH; ++h) {
#pragma unroll
            for (int i = 0; i < DH; ++i) H[h * DH + i] = xh[(h0 + h) * DH + i];
        }
#pragma unroll 1
        for (int s = 0; s < 32; ++s) {
            float b[DS];
#pragma unroll
            for (int j = 0; j < DS; ++j) b[j] = xs[s * DS + j];
            float c[DH];
#pragma unroll
            for (int i = 0; i < DH; ++i) {
                float t = 0.f;
#pragma unroll
                for (int j = 0; j < DS; ++j) t = fmaf(w3l[i][j], b[j], t);
                c[i] = t;
            }
            const float* wbase = Wp + (HX1 ? s * 32 : s * 1024);
#pragma unroll
            for (int h = 0; h < CH; ++h) {
                float o = 0.f;
#pragma unroll
                for (int i = 0; i < DH; ++i) o = fmaf(c[i], H[h * DH + i], o);
                const float* wr = wbase + (HX1 ? (h0 + h) * 1024 : (h0 + h) * 32);
#pragma unroll
                for (int w = 0; w < NW; ++w) acc[w] = fmaf(wr[w], o, acc[w]);
            }
        }
    }
}

__global__ __launch_bounds__(64, 2) void tp_main(const float* __restrict__ x1,
                                                 const float* __restrict__ x2,
                                                 const float* __restrict__ W,
                                                 float* __restrict__ out) {
    const int z = blockIdx.x * 64 + threadIdx.x;
    const float* r1 = x1 + (size_t)z * 288;
    const float* r2 = x2 + (size_t)z * 288;
    const int w0 = blockIdx.z * 16;
    const float* w3t = g_w3;

    float acc[16];
#pragma unroll
    for (int i = 0; i < 16; ++i) acc[i] = 0.f;

    const int arm = blockIdx.y;
    int io, k;
    if (arm == 0)      { io = 0; k = 0; }
    else if (arm <= 3) { io = 1; k = arm - 1; }
    else               { io = 2; k = arm - 4; }

    if (io == 0) {
        // (0,0,0): hold x2(l0), stream x1(l0)
        do_path<1, 1, 1, 1, 1, false, 16>(r2 + 0,   r1 + 0,   W + 0 * 32768 + w0,  w3t + 0 * 128, 0, acc);
        // (1,1,0): hold x2(l1), stream x1(l1)
        do_path<3, 3, 3, 3, 1, false, 16>(r2 + 32,  r1 + 32,  W + 4 * 32768 + w0,  w3t + 4 * 128, 0, acc);
        // (2,2,0): hold x2(l2), stream x1(l2)
        do_path<5, 5, 5, 5, 1, false, 16>(r2 + 128, r1 + 128, W + 9 * 32768 + w0,  w3t + 9 * 128, 0, acc);
    } else if (io == 1) {
        // (0,1,1): hold x1(l0), stream x2(l1)
        do_path<1, 3, 1, 3, 3, true,  16>(r1 + 0,   r2 + 32,  W + 1 * 32768 + w0,  w3t + 1 * 128, k, acc);
        // (1,0,1): hold x2(l0), stream x1(l1)
        do_path<1, 3, 3, 1, 3, false, 16>(r2 + 0,   r1 + 32,  W + 3 * 32768 + w0,  w3t + 3 * 128, k, acc);
        // (1,2,1): hold x1(l1), stream x2(l2)
        do_path<3, 5, 3, 5, 3, true,  16>(r1 + 32,  r2 + 128, W + 6 * 32768 + w0,  w3t + 6 * 128, k, acc);
        // (2,1,1): hold x2(l1), stream x1(l2)
        do_path<3, 5, 5, 3, 3, false, 16>(r2 + 32,  r1 + 128, W + 8 * 32768 + w0,  w3t + 8 * 128, k, acc);
    } else {
        // (0,2,2): hold x1(l0), stream x2(l2)
        do_path<1, 5, 1, 5, 5, true,  16>(r1 + 0,   r2 + 128, W + 2 * 32768 + w0,  w3t + 2 * 128, k, acc);
        // (1,1,2): hold x2(l1), stream x1(l1)
        do_path<3, 3, 3, 3, 5, false, 16>(r2 + 32,  r1 + 32,  W + 5 * 32768 + w0,  w3t + 5 * 128, k, acc);
        // (2,0,2): hold x2(l0), stream x1(l2)
        do_path<1, 5, 5, 1, 5, false, 16>(r2 + 0,   r1 + 128, W + 7 * 32768 + w0,  w3t + 7 * 128, k, acc);
        // (2,2,2): hold x2(l2), stream x1(l2)
        do_path<5, 5, 5, 5, 5, false, 16>(r2 + 128, r1 + 128, W + 10 * 32768 + w0, w3t + 10 * 128, k, acc);
    }

    // epilogue: alpha = sqrt((2lo+1)/fan_in)
    const float alpha = (io == 0) ? 0.018042196f : ((io == 1) ? 0.027063294f : 0.034938562f);
    const int off_o   = (io == 0) ? 0 : ((io == 1) ? 32 : 128);
    const int DOd     = (io == 0) ? 1 : ((io == 1) ? 3 : 5);
    float* orow = out + (size_t)z * 288 + off_o + k;
#pragma unroll
    for (int w = 0; w < 16; ++w) orow[(w0 + w) * DOd] = alpha * acc[w];
}

// ---------------- launch -----------------------------------------------------

extern "C" void kernel_launch(void* const* d_in, const int* in_sizes, int n_in,
                              void* d_out, int out_size, void* d_ws, size_t ws_size,
                              hipStream_t stream) {
    const float* x1 = (const float*)d_in[0];
    const float* x2 = (const float*)d_in[1];
    const float* W  = (const float*)d_in[2];
    float* out = (float*)d_out;

    wigner3j_setup<<<dim3(11), dim3(128), 0, stream>>>();
    tp_main<<<dim3(128, 9, 2), dim3(64), 0, stream>>>(x1, x2, W, out);
}